// Round 2
// baseline (890.355 us; speedup 1.0000x reference)
//
#include <hip/hip_runtime.h>

#define SEQ 512
#define BATCH 256
#define INDIM 256
#define MLP 128
#define M_ROWS (SEQ * BATCH)        // 131072
#define PRE_STRIDE 136              // 128 mlp-pre + 4 gate-pre + 4 pad
#define AUX_OFF ((size_t)M_ROWS * PRE_STRIDE)  // in floats

// ---------------------------------------------------------------------------
// Kernel 1: prep — column sums of the recurrent halves of W1 and gate weights.
// ---------------------------------------------------------------------------
__global__ __launch_bounds__(256) void prep_kernel(
    const float* __restrict__ W1,
    const float* __restrict__ Wf, const float* __restrict__ Wi,
    const float* __restrict__ Wg, const float* __restrict__ Wo,
    const float* __restrict__ bf, const float* __restrict__ bi,
    const float* __restrict__ bg, const float* __restrict__ bo,
    float* __restrict__ aux) {
  const int tid = threadIdx.x;
  if (tid < 128) {
    float s = 0.f;
    for (int k = 0; k < 256; ++k) s += W1[(size_t)(256 + k) * 128 + tid];
    aux[tid] = s;
  } else if (tid < 132) {
    const int g = tid - 128;
    const float* w = (g == 0) ? Wf : (g == 1) ? Wi : (g == 2) ? Wg : Wo;
    float s = 0.f;
    for (int k = 0; k < 256; ++k) s += w[256 + k];
    aux[128 + g] = s;
  } else if (tid < 136) {
    const int g = tid - 132;
    const float* bp = (g == 0) ? bf : (g == 1) ? bi : (g == 2) ? bg : bo;
    aux[132 + g] = bp[0];
  }
}

// ---------------------------------------------------------------------------
// Kernel 2: big fp32 GEMM over all (t,b) rows. (unchanged this round)
// ---------------------------------------------------------------------------
#define BK 16
#define LDX 132  // padded LDS row stride (words)

__global__ __launch_bounds__(256) void gemm_kernel(
    const float* __restrict__ X,    // [M_ROWS][256]
    const float* __restrict__ W1,   // [512][128] (only rows 0..255 used here)
    const float* __restrict__ b1p,  // [128]
    const float* __restrict__ Wf, const float* __restrict__ Wi,
    const float* __restrict__ Wg, const float* __restrict__ Wo,
    const float* __restrict__ bfp, const float* __restrict__ bip,
    const float* __restrict__ bgp, const float* __restrict__ bop,
    float* __restrict__ PRE) {
  __shared__ __align__(16) float Xs[BK * LDX];   // [kk][row], row-padded
  __shared__ __align__(16) float Ws[BK * LDX];   // [kk][col]
  __shared__ float Wgs[BK * 4];                  // [kk][gate]

  const int tid = threadIdx.x;
  const int blk = blockIdx.x;
  const int tx = tid & 15, ty = tid >> 4;       // 16x16 thread grid
  const int r_st = tid >> 1, kh = (tid & 1) * 8; // X staging role
  const int wk = tid >> 4, wn = (tid & 15) * 8;  // W staging role
  const int r2 = tid >> 1, gp = (tid & 1) * 2;   // gate compute role

  const size_t rowbase = (size_t)blk * 128;

  float acc[8][8] = {};
  float ga = 0.f, gb = 0.f;

  for (int kc = 0; kc < 256; kc += BK) {
    const float4 xa = *(const float4*)&X[(rowbase + r_st) * 256 + kc + kh];
    const float4 xb = *(const float4*)&X[(rowbase + r_st) * 256 + kc + kh + 4];
    const float4 wa = *(const float4*)&W1[(size_t)(kc + wk) * 128 + wn];
    const float4 wb = *(const float4*)&W1[(size_t)(kc + wk) * 128 + wn + 4];
    float wgv = 0.f;
    if (tid < 64) {
      const int kk = tid >> 2, g = tid & 3;
      const float* w = (g == 0) ? Wf : (g == 1) ? Wi : (g == 2) ? Wg : Wo;
      wgv = w[kc + kk];
    }
    __syncthreads();  // previous chunk's compute must be done before overwrite
    Xs[(kh + 0) * LDX + r_st] = xa.x;
    Xs[(kh + 1) * LDX + r_st] = xa.y;
    Xs[(kh + 2) * LDX + r_st] = xa.z;
    Xs[(kh + 3) * LDX + r_st] = xa.w;
    Xs[(kh + 4) * LDX + r_st] = xb.x;
    Xs[(kh + 5) * LDX + r_st] = xb.y;
    Xs[(kh + 6) * LDX + r_st] = xb.z;
    Xs[(kh + 7) * LDX + r_st] = xb.w;
    *(float4*)&Ws[wk * LDX + wn] = wa;
    *(float4*)&Ws[wk * LDX + wn + 4] = wb;
    if (tid < 64) Wgs[tid] = wgv;
    __syncthreads();

#pragma unroll
    for (int kk = 0; kk < BK; ++kk) {
      const float4 a0 = *(const float4*)&Xs[kk * LDX + ty * 8];
      const float4 a1 = *(const float4*)&Xs[kk * LDX + ty * 8 + 4];
      const float4 c0 = *(const float4*)&Ws[kk * LDX + tx * 8];
      const float4 c1 = *(const float4*)&Ws[kk * LDX + tx * 8 + 4];
      const float av[8] = {a0.x, a0.y, a0.z, a0.w, a1.x, a1.y, a1.z, a1.w};
      const float bv[8] = {c0.x, c0.y, c0.z, c0.w, c1.x, c1.y, c1.z, c1.w};
#pragma unroll
      for (int i = 0; i < 8; ++i)
#pragma unroll
        for (int j = 0; j < 8; ++j)
          acc[i][j] = fmaf(av[i], bv[j], acc[i][j]);
      const float xv = Xs[kk * LDX + r2];
      ga = fmaf(xv, Wgs[kk * 4 + gp], ga);
      gb = fmaf(xv, Wgs[kk * 4 + gp + 1], gb);
    }
  }

  float bias[8];
  {
    const float4 u0 = *(const float4*)&b1p[tx * 8];
    const float4 u1 = *(const float4*)&b1p[tx * 8 + 4];
    bias[0] = u0.x; bias[1] = u0.y; bias[2] = u0.z; bias[3] = u0.w;
    bias[4] = u1.x; bias[5] = u1.y; bias[6] = u1.z; bias[7] = u1.w;
  }
#pragma unroll
  for (int i = 0; i < 8; ++i) {
    const size_t row = rowbase + ty * 8 + i;
    float4 o0, o1;
    o0.x = acc[i][0] + bias[0]; o0.y = acc[i][1] + bias[1];
    o0.z = acc[i][2] + bias[2]; o0.w = acc[i][3] + bias[3];
    o1.x = acc[i][4] + bias[4]; o1.y = acc[i][5] + bias[5];
    o1.z = acc[i][6] + bias[6]; o1.w = acc[i][7] + bias[7];
    *(float4*)&PRE[row * PRE_STRIDE + tx * 8] = o0;
    *(float4*)&PRE[row * PRE_STRIDE + tx * 8 + 4] = o1;
  }
  {
    const float bf0 = bfp[0], bi0 = bip[0], bg0 = bgp[0], bo0 = bop[0];
    const float ab = (gp == 0) ? bf0 : bg0;
    const float bb = (gp == 0) ? bi0 : bo0;
    const size_t row = rowbase + r2;
    float2 og;
    og.x = ga + ab; og.y = gb + bb;
    *(float2*)&PRE[row * PRE_STRIDE + 128 + gp] = og;
  }
}

// ---------------------------------------------------------------------------
// Kernel 3: serial recurrence. One wave (64 lanes) per batch element.
// Single-wave block => NO s_barrier needed. __syncthreads() would emit
// s_waitcnt vmcnt(0) expcnt(0) lgkmcnt(0) + s_barrier, draining the
// distance-3 global prefetch and the output stores every step (~2700 cy/step
// observed in R1). Replace with a raw lgkmcnt(0) wait: DS ops are in-order
// per wave, so write -> lgkmcnt(0) -> read is a correct cross-lane fence and
// leaves vmcnt/expcnt untouched.
// ---------------------------------------------------------------------------
__device__ __forceinline__ void lds_fence_wave() {
  asm volatile("s_waitcnt lgkmcnt(0)" ::: "memory");
}

__device__ __forceinline__ float sigmoid_f(float x) {
  return __fdividef(1.0f, 1.0f + __expf(-x));
}
__device__ __forceinline__ float tanh_f(float x) {
  const float e = __expf(-2.0f * x);
  return __fdividef(1.0f - e, 1.0f + e);
}
__device__ __forceinline__ float qgate_f(const float* c) {
  float p = c[0], s = c[0];
#pragma unroll
  for (int k = 1; k < 8; ++k) { p *= c[k]; s += p; }
  return s * 0.125f;
}

__global__ __launch_bounds__(64) void rec_kernel(
    const float* __restrict__ PRE, const float* __restrict__ W2,
    const float* __restrict__ b2, const float* __restrict__ aux,
    float* __restrict__ out) {
  __shared__ __align__(16) float h1s[128];
  __shared__ __align__(16) float csh[32];

  const int l = threadIdx.x;
  const int b = blockIdx.x;
  const int m = l & 31, half = l >> 5;

  // W2 fragment: lane (m, half) holds W2[half*64+u][m], u=0..63
  float w2r[64];
#pragma unroll
  for (int u = 0; u < 64; ++u) w2r[u] = W2[(size_t)(half * 64 + u) * 32 + m];
  const float b2v = b2[m];
  const float2 s1 = *(const float2*)&aux[2 * l];
  const float4 sg = *(const float4*)&aux[128];  // sf, si, sg, so

  float h = 0.f, c = 0.f;

  const float* pr0 = PRE + (size_t)b * PRE_STRIDE;
  const size_t tstride = (size_t)BATCH * PRE_STRIDE;

  // depth-3 prefetch pipeline
  float2 p0 = *(const float2*)(pr0 + 0 * tstride + 2 * l);
  float4 g0 = *(const float4*)(pr0 + 0 * tstride + 128);
  float2 p1 = *(const float2*)(pr0 + 1 * tstride + 2 * l);
  float4 g1 = *(const float4*)(pr0 + 1 * tstride + 128);
  float2 p2 = *(const float2*)(pr0 + 2 * tstride + 2 * l);
  float4 g2 = *(const float4*)(pr0 + 2 * tstride + 128);

  for (int t = 0; t < SEQ; ++t) {
    // h1 = relu(pre + h*s1)   (b1 already folded into PRE)
    const float h10 = fmaxf(fmaf(h, s1.x, p0.x), 0.f);
    const float h11 = fmaxf(fmaf(h, s1.y, p0.y), 0.f);
    // classical gate pre-activations
    const float zf = fmaf(h, sg.x, g0.x);
    const float zi = fmaf(h, sg.y, g0.y);
    const float zg = fmaf(h, sg.z, g0.z);
    const float zo = fmaf(h, sg.w, g0.w);
    // rotate prefetch (distance 3)
    p0 = p1; g0 = g1; p1 = p2; g1 = g2;
    const int tn = (t + 3 < SEQ) ? (t + 3) : (SEQ - 1);
    p2 = *(const float2*)(pr0 + (size_t)tn * tstride + 2 * l);
    g2 = *(const float4*)(pr0 + (size_t)tn * tstride + 128);

    // broadcast h1 through LDS (wave-level fence, no barrier)
    ((float2*)h1s)[l] = make_float2(h10, h11);
    lds_fence_wave();

    // q[m] = sum_j h1[j] * W2[j][m]  — each (m,half) lane sums 64 j's
    float q0 = 0.f, q1 = 0.f, q2 = 0.f, q3 = 0.f;
    const float4* hv4 = (const float4*)&h1s[half * 64];
#pragma unroll
    for (int jj = 0; jj < 16; ++jj) {
      const float4 hv = hv4[jj];
      q0 = fmaf(hv.x, w2r[4 * jj + 0], q0);
      q1 = fmaf(hv.y, w2r[4 * jj + 1], q1);
      q2 = fmaf(hv.z, w2r[4 * jj + 2], q2);
      q3 = fmaf(hv.w, w2r[4 * jj + 3], q3);
    }
    const float qh = (q0 + q1) + (q2 + q3);
    const float theta = qh + __shfl_xor(qh, 32, 64) + b2v;
    const float cv = __cosf(theta);
    if (l < 32) csh[m] = cv;
    lds_fence_wave();

    // every lane reads all 32 cos values and does the 4 qgates serially
    float cc[32];
#pragma unroll
    for (int u = 0; u < 8; ++u) {
      const float4 v = ((const float4*)csh)[u];
      cc[4 * u + 0] = v.x; cc[4 * u + 1] = v.y;
      cc[4 * u + 2] = v.z; cc[4 * u + 3] = v.w;
    }
    const float qf = qgate_f(cc + 0);
    const float qi = qgate_f(cc + 8);
    const float qg = qgate_f(cc + 16);
    const float qo = qgate_f(cc + 24);

    const float f  = 0.5f * (sigmoid_f(zf) + sigmoid_f(qf));
    const float ii = 0.5f * (sigmoid_f(zi) + sigmoid_f(qi));
    const float gg = 0.5f * (tanh_f(zg) + tanh_f(qg));
    const float oo = 0.5f * (sigmoid_f(zo) + sigmoid_f(qo));

    c = fmaf(f, c, ii * gg);
    h = oo * tanh_f(c);

    float4 hv4o; hv4o.x = h; hv4o.y = h; hv4o.z = h; hv4o.w = h;
    *(float4*)(out + ((size_t)t * BATCH + b) * 256 + 4 * l) = hv4o;
  }

  // final (hx, cx) outputs
  float4 hq; hq.x = h; hq.y = h; hq.z = h; hq.w = h;
  float4 cq; cq.x = c; cq.y = c; cq.z = c; cq.w = c;
  *(float4*)(out + (size_t)SEQ * BATCH * 256 + (size_t)b * 256 + 4 * l) = hq;
  *(float4*)(out + (size_t)SEQ * BATCH * 256 + (size_t)BATCH * 256 +
             (size_t)b * 256 + 4 * l) = cq;
}

// ---------------------------------------------------------------------------
extern "C" void kernel_launch(void* const* d_in, const int* in_sizes, int n_in,
                              void* d_out, int out_size, void* d_ws,
                              size_t ws_size, hipStream_t stream) {
  const float* X  = (const float*)d_in[0];
  const float* W1 = (const float*)d_in[1];
  const float* b1 = (const float*)d_in[2];
  const float* W2 = (const float*)d_in[3];
  const float* b2 = (const float*)d_in[4];
  const float* Wf = (const float*)d_in[5];
  const float* bf = (const float*)d_in[6];
  const float* Wi = (const float*)d_in[7];
  const float* bi = (const float*)d_in[8];
  const float* Wg = (const float*)d_in[9];
  const float* bg = (const float*)d_in[10];
  const float* Wo = (const float*)d_in[11];
  const float* bo = (const float*)d_in[12];

  float* ws  = (float*)d_ws;
  float* PRE = ws;
  float* aux = ws + AUX_OFF;
  float* out = (float*)d_out;

  prep_kernel<<<1, 256, 0, stream>>>(W1, Wf, Wi, Wg, Wo, bf, bi, bg, bo, aux);
  gemm_kernel<<<M_ROWS / 128, 256, 0, stream>>>(X, W1, b1, Wf, Wi, Wg, Wo,
                                                bf, bi, bg, bo, PRE);
  rec_kernel<<<BATCH, 64, 0, stream>>>(PRE, W2, b2, aux, out);
}

// Round 3
// 890.006 us; speedup vs baseline: 1.0004x; 1.0004x over previous
//
#include <hip/hip_runtime.h>

#define SEQ 512
#define BATCH 256
#define INDIM 256
#define MLP 128
#define M_ROWS (SEQ * BATCH)        // 131072
#define PRE_STRIDE 136              // 128 mlp-pre + 4 gate-pre + 4 pad
#define AUX_OFF ((size_t)M_ROWS * PRE_STRIDE)  // in floats

// ---------------------------------------------------------------------------
// Kernel 1: prep — column sums of the recurrent halves of W1 and gate weights.
// ---------------------------------------------------------------------------
__global__ __launch_bounds__(256) void prep_kernel(
    const float* __restrict__ W1,
    const float* __restrict__ Wf, const float* __restrict__ Wi,
    const float* __restrict__ Wg, const float* __restrict__ Wo,
    const float* __restrict__ bf, const float* __restrict__ bi,
    const float* __restrict__ bg, const float* __restrict__ bo,
    float* __restrict__ aux) {
  const int tid = threadIdx.x;
  if (tid < 128) {
    float s = 0.f;
    for (int k = 0; k < 256; ++k) s += W1[(size_t)(256 + k) * 128 + tid];
    aux[tid] = s;
  } else if (tid < 132) {
    const int g = tid - 128;
    const float* w = (g == 0) ? Wf : (g == 1) ? Wi : (g == 2) ? Wg : Wo;
    float s = 0.f;
    for (int k = 0; k < 256; ++k) s += w[256 + k];
    aux[128 + g] = s;
  } else if (tid < 136) {
    const int g = tid - 132;
    const float* bp = (g == 0) ? bf : (g == 1) ? bi : (g == 2) ? bg : bo;
    aux[132 + g] = bp[0];
  }
}

// ---------------------------------------------------------------------------
// Kernel 2: big fp32 GEMM over all (t,b) rows. (unchanged this round)
// ---------------------------------------------------------------------------
#define BK 16
#define LDX 132  // padded LDS row stride (words)

__global__ __launch_bounds__(256) void gemm_kernel(
    const float* __restrict__ X,    // [M_ROWS][256]
    const float* __restrict__ W1,   // [512][128] (only rows 0..255 used here)
    const float* __restrict__ b1p,  // [128]
    const float* __restrict__ Wf, const float* __restrict__ Wi,
    const float* __restrict__ Wg, const float* __restrict__ Wo,
    const float* __restrict__ bfp, const float* __restrict__ bip,
    const float* __restrict__ bgp, const float* __restrict__ bop,
    float* __restrict__ PRE) {
  __shared__ __align__(16) float Xs[BK * LDX];   // [kk][row], row-padded
  __shared__ __align__(16) float Ws[BK * LDX];   // [kk][col]
  __shared__ float Wgs[BK * 4];                  // [kk][gate]

  const int tid = threadIdx.x;
  const int blk = blockIdx.x;
  const int tx = tid & 15, ty = tid >> 4;       // 16x16 thread grid
  const int r_st = tid >> 1, kh = (tid & 1) * 8; // X staging role
  const int wk = tid >> 4, wn = (tid & 15) * 8;  // W staging role
  const int r2 = tid >> 1, gp = (tid & 1) * 2;   // gate compute role

  const size_t rowbase = (size_t)blk * 128;

  float acc[8][8] = {};
  float ga = 0.f, gb = 0.f;

  for (int kc = 0; kc < 256; kc += BK) {
    const float4 xa = *(const float4*)&X[(rowbase + r_st) * 256 + kc + kh];
    const float4 xb = *(const float4*)&X[(rowbase + r_st) * 256 + kc + kh + 4];
    const float4 wa = *(const float4*)&W1[(size_t)(kc + wk) * 128 + wn];
    const float4 wb = *(const float4*)&W1[(size_t)(kc + wk) * 128 + wn + 4];
    float wgv = 0.f;
    if (tid < 64) {
      const int kk = tid >> 2, g = tid & 3;
      const float* w = (g == 0) ? Wf : (g == 1) ? Wi : (g == 2) ? Wg : Wo;
      wgv = w[kc + kk];
    }
    __syncthreads();  // previous chunk's compute must be done before overwrite
    Xs[(kh + 0) * LDX + r_st] = xa.x;
    Xs[(kh + 1) * LDX + r_st] = xa.y;
    Xs[(kh + 2) * LDX + r_st] = xa.z;
    Xs[(kh + 3) * LDX + r_st] = xa.w;
    Xs[(kh + 4) * LDX + r_st] = xb.x;
    Xs[(kh + 5) * LDX + r_st] = xb.y;
    Xs[(kh + 6) * LDX + r_st] = xb.z;
    Xs[(kh + 7) * LDX + r_st] = xb.w;
    *(float4*)&Ws[wk * LDX + wn] = wa;
    *(float4*)&Ws[wk * LDX + wn + 4] = wb;
    if (tid < 64) Wgs[tid] = wgv;
    __syncthreads();

#pragma unroll
    for (int kk = 0; kk < BK; ++kk) {
      const float4 a0 = *(const float4*)&Xs[kk * LDX + ty * 8];
      const float4 a1 = *(const float4*)&Xs[kk * LDX + ty * 8 + 4];
      const float4 c0 = *(const float4*)&Ws[kk * LDX + tx * 8];
      const float4 c1 = *(const float4*)&Ws[kk * LDX + tx * 8 + 4];
      const float av[8] = {a0.x, a0.y, a0.z, a0.w, a1.x, a1.y, a1.z, a1.w};
      const float bv[8] = {c0.x, c0.y, c0.z, c0.w, c1.x, c1.y, c1.z, c1.w};
#pragma unroll
      for (int i = 0; i < 8; ++i)
#pragma unroll
        for (int j = 0; j < 8; ++j)
          acc[i][j] = fmaf(av[i], bv[j], acc[i][j]);
      const float xv = Xs[kk * LDX + r2];
      ga = fmaf(xv, Wgs[kk * 4 + gp], ga);
      gb = fmaf(xv, Wgs[kk * 4 + gp + 1], gb);
    }
  }

  float bias[8];
  {
    const float4 u0 = *(const float4*)&b1p[tx * 8];
    const float4 u1 = *(const float4*)&b1p[tx * 8 + 4];
    bias[0] = u0.x; bias[1] = u0.y; bias[2] = u0.z; bias[3] = u0.w;
    bias[4] = u1.x; bias[5] = u1.y; bias[6] = u1.z; bias[7] = u1.w;
  }
#pragma unroll
  for (int i = 0; i < 8; ++i) {
    const size_t row = rowbase + ty * 8 + i;
    float4 o0, o1;
    o0.x = acc[i][0] + bias[0]; o0.y = acc[i][1] + bias[1];
    o0.z = acc[i][2] + bias[2]; o0.w = acc[i][3] + bias[3];
    o1.x = acc[i][4] + bias[4]; o1.y = acc[i][5] + bias[5];
    o1.z = acc[i][6] + bias[6]; o1.w = acc[i][7] + bias[7];
    *(float4*)&PRE[row * PRE_STRIDE + tx * 8] = o0;
    *(float4*)&PRE[row * PRE_STRIDE + tx * 8 + 4] = o1;
  }
  {
    const float bf0 = bfp[0], bi0 = bip[0], bg0 = bgp[0], bo0 = bop[0];
    const float ab = (gp == 0) ? bf0 : bg0;
    const float bb = (gp == 0) ? bi0 : bo0;
    const size_t row = rowbase + r2;
    float2 og;
    og.x = ga + ab; og.y = gb + bb;
    *(float2*)&PRE[row * PRE_STRIDE + 128 + gp] = og;
  }
}

// ---------------------------------------------------------------------------
// Kernel 3: serial recurrence. One wave (64 lanes) per batch element.
// R2 post-mortem: VGPR_Count=64 => the compiler spilled w2r[64]+cc[32] to
// scratch and re-loaded ~16KB/wave/step through L1 — THAT was the ~2700
// cy/step, not the barrier. Fix: __launch_bounds__(64, 1) (min 1 wave/EU =>
// full 512-VGPR budget; we only run 1 wave/CU anyway) and no indexable
// arrays in the loop body.
// ---------------------------------------------------------------------------
__device__ __forceinline__ void lds_fence_wave() {
  asm volatile("s_waitcnt lgkmcnt(0)" ::: "memory");
}

__device__ __forceinline__ float sigmoid_f(float x) {
  return __fdividef(1.0f, 1.0f + __expf(-x));
}
__device__ __forceinline__ float tanh_f(float x) {
  const float e = __expf(-2.0f * x);
  return __fdividef(1.0f - e, 1.0f + e);
}
// cumprod-of-8 mean from two float4s (no memory array)
__device__ __forceinline__ float qgate_v(const float4 a, const float4 b) {
  float p = a.x, s = a.x;
  p *= a.y; s += p;
  p *= a.z; s += p;
  p *= a.w; s += p;
  p *= b.x; s += p;
  p *= b.y; s += p;
  p *= b.z; s += p;
  p *= b.w; s += p;
  return s * 0.125f;
}

__global__ __launch_bounds__(64, 1) void rec_kernel(
    const float* __restrict__ PRE, const float* __restrict__ W2,
    const float* __restrict__ b2, const float* __restrict__ aux,
    float* __restrict__ out) {
  __shared__ __align__(16) float h1s[128];
  __shared__ __align__(16) float csh[32];

  const int l = threadIdx.x;
  const int b = blockIdx.x;
  const int m = l & 31, half = l >> 5;

  // W2 fragment: lane (m, half) holds W2[half*64+u][m], u=0..63
  float w2r[64];
#pragma unroll
  for (int u = 0; u < 64; ++u) w2r[u] = W2[(size_t)(half * 64 + u) * 32 + m];
  const float b2v = b2[m];
  const float2 s1 = *(const float2*)&aux[2 * l];
  const float4 sg = *(const float4*)&aux[128];  // sf, si, sg, so

  float h = 0.f, c = 0.f;

  const float* pr0 = PRE + (size_t)b * PRE_STRIDE;
  const size_t tstride = (size_t)BATCH * PRE_STRIDE;

  // depth-3 prefetch pipeline
  float2 p0 = *(const float2*)(pr0 + 0 * tstride + 2 * l);
  float4 g0 = *(const float4*)(pr0 + 0 * tstride + 128);
  float2 p1 = *(const float2*)(pr0 + 1 * tstride + 2 * l);
  float4 g1 = *(const float4*)(pr0 + 1 * tstride + 128);
  float2 p2 = *(const float2*)(pr0 + 2 * tstride + 2 * l);
  float4 g2 = *(const float4*)(pr0 + 2 * tstride + 128);

  for (int t = 0; t < SEQ; ++t) {
    // h1 = relu(pre + h*s1)   (b1 already folded into PRE)
    const float h10 = fmaxf(fmaf(h, s1.x, p0.x), 0.f);
    const float h11 = fmaxf(fmaf(h, s1.y, p0.y), 0.f);
    // classical gate pre-activations
    const float zf = fmaf(h, sg.x, g0.x);
    const float zi = fmaf(h, sg.y, g0.y);
    const float zg = fmaf(h, sg.z, g0.z);
    const float zo = fmaf(h, sg.w, g0.w);
    // rotate prefetch (distance 3)
    p0 = p1; g0 = g1; p1 = p2; g1 = g2;
    const int tn = (t + 3 < SEQ) ? (t + 3) : (SEQ - 1);
    p2 = *(const float2*)(pr0 + (size_t)tn * tstride + 2 * l);
    g2 = *(const float4*)(pr0 + (size_t)tn * tstride + 128);

    // broadcast h1 through LDS (wave-level fence, no barrier)
    ((float2*)h1s)[l] = make_float2(h10, h11);
    lds_fence_wave();

    // q[m] = sum_j h1[j] * W2[j][m]  — each (m,half) lane sums 64 j's
    float q0 = 0.f, q1 = 0.f, q2 = 0.f, q3 = 0.f;
    const float4* hv4 = (const float4*)&h1s[half * 64];
#pragma unroll
    for (int jj = 0; jj < 16; ++jj) {
      const float4 hv = hv4[jj];
      q0 = fmaf(hv.x, w2r[4 * jj + 0], q0);
      q1 = fmaf(hv.y, w2r[4 * jj + 1], q1);
      q2 = fmaf(hv.z, w2r[4 * jj + 2], q2);
      q3 = fmaf(hv.w, w2r[4 * jj + 3], q3);
    }
    const float qh = (q0 + q1) + (q2 + q3);
    const float theta = qh + __shfl_xor(qh, 32, 64) + b2v;
    const float cv = __cosf(theta);
    if (l < 32) csh[m] = cv;
    lds_fence_wave();

    // every lane reads all 32 cos values (8 float4s, named regs — no array)
    const float4 c0v = ((const float4*)csh)[0];
    const float4 c1v = ((const float4*)csh)[1];
    const float4 c2v = ((const float4*)csh)[2];
    const float4 c3v = ((const float4*)csh)[3];
    const float4 c4v = ((const float4*)csh)[4];
    const float4 c5v = ((const float4*)csh)[5];
    const float4 c6v = ((const float4*)csh)[6];
    const float4 c7v = ((const float4*)csh)[7];
    const float qf = qgate_v(c0v, c1v);
    const float qi = qgate_v(c2v, c3v);
    const float qg = qgate_v(c4v, c5v);
    const float qo = qgate_v(c6v, c7v);

    const float f  = 0.5f * (sigmoid_f(zf) + sigmoid_f(qf));
    const float ii = 0.5f * (sigmoid_f(zi) + sigmoid_f(qi));
    const float gg = 0.5f * (tanh_f(zg) + tanh_f(qg));
    const float oo = 0.5f * (sigmoid_f(zo) + sigmoid_f(qo));

    c = fmaf(f, c, ii * gg);
    h = oo * tanh_f(c);

    float4 hv4o; hv4o.x = h; hv4o.y = h; hv4o.z = h; hv4o.w = h;
    *(float4*)(out + ((size_t)t * BATCH + b) * 256 + 4 * l) = hv4o;
  }

  // final (hx, cx) outputs
  float4 hq; hq.x = h; hq.y = h; hq.z = h; hq.w = h;
  float4 cq; cq.x = c; cq.y = c; cq.z = c; cq.w = c;
  *(float4*)(out + (size_t)SEQ * BATCH * 256 + (size_t)b * 256 + 4 * l) = hq;
  *(float4*)(out + (size_t)SEQ * BATCH * 256 + (size_t)BATCH * 256 +
             (size_t)b * 256 + 4 * l) = cq;
}

// ---------------------------------------------------------------------------
extern "C" void kernel_launch(void* const* d_in, const int* in_sizes, int n_in,
                              void* d_out, int out_size, void* d_ws,
                              size_t ws_size, hipStream_t stream) {
  const float* X  = (const float*)d_in[0];
  const float* W1 = (const float*)d_in[1];
  const float* b1 = (const float*)d_in[2];
  const float* W2 = (const float*)d_in[3];
  const float* b2 = (const float*)d_in[4];
  const float* Wf = (const float*)d_in[5];
  const float* bf = (const float*)d_in[6];
  const float* Wi = (const float*)d_in[7];
  const float* bi = (const float*)d_in[8];
  const float* Wg = (const float*)d_in[9];
  const float* bg = (const float*)d_in[10];
  const float* Wo = (const float*)d_in[11];
  const float* bo = (const float*)d_in[12];

  float* ws  = (float*)d_ws;
  float* PRE = ws;
  float* aux = ws + AUX_OFF;
  float* out = (float*)d_out;

  prep_kernel<<<1, 256, 0, stream>>>(W1, Wf, Wi, Wg, Wo, bf, bi, bg, bo, aux);
  gemm_kernel<<<M_ROWS / 128, 256, 0, stream>>>(X, W1, b1, Wf, Wi, Wg, Wo,
                                                bf, bi, bg, bo, PRE);
  rec_kernel<<<BATCH, 64, 0, stream>>>(PRE, W2, b2, aux, out);
}

// Round 4
// 862.639 us; speedup vs baseline: 1.0321x; 1.0317x over previous
//
#include <hip/hip_runtime.h>

#define SEQ 512
#define BATCH 256
#define INDIM 256
#define MLP 128
#define M_ROWS (SEQ * BATCH)        // 131072
#define PRE_STRIDE 136              // 128 mlp-pre + 4 gate-pre + 4 pad
#define AUX_OFF ((size_t)M_ROWS * PRE_STRIDE)  // in floats

// ---------------------------------------------------------------------------
// Kernel 1: prep — column sums of the recurrent halves of W1 and gate weights.
// ---------------------------------------------------------------------------
__global__ __launch_bounds__(256) void prep_kernel(
    const float* __restrict__ W1,
    const float* __restrict__ Wf, const float* __restrict__ Wi,
    const float* __restrict__ Wg, const float* __restrict__ Wo,
    const float* __restrict__ bf, const float* __restrict__ bi,
    const float* __restrict__ bg, const float* __restrict__ bo,
    float* __restrict__ aux) {
  const int tid = threadIdx.x;
  if (tid < 128) {
    float s = 0.f;
    for (int k = 0; k < 256; ++k) s += W1[(size_t)(256 + k) * 128 + tid];
    aux[tid] = s;
  } else if (tid < 132) {
    const int g = tid - 128;
    const float* w = (g == 0) ? Wf : (g == 1) ? Wi : (g == 2) ? Wg : Wo;
    float s = 0.f;
    for (int k = 0; k < 256; ++k) s += w[256 + k];
    aux[128 + g] = s;
  } else if (tid < 136) {
    const int g = tid - 132;
    const float* bp = (g == 0) ? bf : (g == 1) ? bi : (g == 2) ? bg : bo;
    aux[132 + g] = bp[0];
  }
}

// ---------------------------------------------------------------------------
// Kernel 2: big fp32 GEMM over all (t,b) rows. (unchanged this round)
// ---------------------------------------------------------------------------
#define BK 16
#define LDX 132  // padded LDS row stride (words)

__global__ __launch_bounds__(256) void gemm_kernel(
    const float* __restrict__ X,    // [M_ROWS][256]
    const float* __restrict__ W1,   // [512][128] (only rows 0..255 used here)
    const float* __restrict__ b1p,  // [128]
    const float* __restrict__ Wf, const float* __restrict__ Wi,
    const float* __restrict__ Wg, const float* __restrict__ Wo,
    const float* __restrict__ bfp, const float* __restrict__ bip,
    const float* __restrict__ bgp, const float* __restrict__ bop,
    float* __restrict__ PRE) {
  __shared__ __align__(16) float Xs[BK * LDX];   // [kk][row], row-padded
  __shared__ __align__(16) float Ws[BK * LDX];   // [kk][col]
  __shared__ float Wgs[BK * 4];                  // [kk][gate]

  const int tid = threadIdx.x;
  const int blk = blockIdx.x;
  const int tx = tid & 15, ty = tid >> 4;       // 16x16 thread grid
  const int r_st = tid >> 1, kh = (tid & 1) * 8; // X staging role
  const int wk = tid >> 4, wn = (tid & 15) * 8;  // W staging role
  const int r2 = tid >> 1, gp = (tid & 1) * 2;   // gate compute role

  const size_t rowbase = (size_t)blk * 128;

  float acc[8][8] = {};
  float ga = 0.f, gb = 0.f;

  for (int kc = 0; kc < 256; kc += BK) {
    const float4 xa = *(const float4*)&X[(rowbase + r_st) * 256 + kc + kh];
    const float4 xb = *(const float4*)&X[(rowbase + r_st) * 256 + kc + kh + 4];
    const float4 wa = *(const float4*)&W1[(size_t)(kc + wk) * 128 + wn];
    const float4 wb = *(const float4*)&W1[(size_t)(kc + wk) * 128 + wn + 4];
    float wgv = 0.f;
    if (tid < 64) {
      const int kk = tid >> 2, g = tid & 3;
      const float* w = (g == 0) ? Wf : (g == 1) ? Wi : (g == 2) ? Wg : Wo;
      wgv = w[kc + kk];
    }
    __syncthreads();  // previous chunk's compute must be done before overwrite
    Xs[(kh + 0) * LDX + r_st] = xa.x;
    Xs[(kh + 1) * LDX + r_st] = xa.y;
    Xs[(kh + 2) * LDX + r_st] = xa.z;
    Xs[(kh + 3) * LDX + r_st] = xa.w;
    Xs[(kh + 4) * LDX + r_st] = xb.x;
    Xs[(kh + 5) * LDX + r_st] = xb.y;
    Xs[(kh + 6) * LDX + r_st] = xb.z;
    Xs[(kh + 7) * LDX + r_st] = xb.w;
    *(float4*)&Ws[wk * LDX + wn] = wa;
    *(float4*)&Ws[wk * LDX + wn + 4] = wb;
    if (tid < 64) Wgs[tid] = wgv;
    __syncthreads();

#pragma unroll
    for (int kk = 0; kk < BK; ++kk) {
      const float4 a0 = *(const float4*)&Xs[kk * LDX + ty * 8];
      const float4 a1 = *(const float4*)&Xs[kk * LDX + ty * 8 + 4];
      const float4 c0 = *(const float4*)&Ws[kk * LDX + tx * 8];
      const float4 c1 = *(const float4*)&Ws[kk * LDX + tx * 8 + 4];
      const float av[8] = {a0.x, a0.y, a0.z, a0.w, a1.x, a1.y, a1.z, a1.w};
      const float bv[8] = {c0.x, c0.y, c0.z, c0.w, c1.x, c1.y, c1.z, c1.w};
#pragma unroll
      for (int i = 0; i < 8; ++i)
#pragma unroll
        for (int j = 0; j < 8; ++j)
          acc[i][j] = fmaf(av[i], bv[j], acc[i][j]);
      const float xv = Xs[kk * LDX + r2];
      ga = fmaf(xv, Wgs[kk * 4 + gp], ga);
      gb = fmaf(xv, Wgs[kk * 4 + gp + 1], gb);
    }
  }

  float bias[8];
  {
    const float4 u0 = *(const float4*)&b1p[tx * 8];
    const float4 u1 = *(const float4*)&b1p[tx * 8 + 4];
    bias[0] = u0.x; bias[1] = u0.y; bias[2] = u0.z; bias[3] = u0.w;
    bias[4] = u1.x; bias[5] = u1.y; bias[6] = u1.z; bias[7] = u1.w;
  }
#pragma unroll
  for (int i = 0; i < 8; ++i) {
    const size_t row = rowbase + ty * 8 + i;
    float4 o0, o1;
    o0.x = acc[i][0] + bias[0]; o0.y = acc[i][1] + bias[1];
    o0.z = acc[i][2] + bias[2]; o0.w = acc[i][3] + bias[3];
    o1.x = acc[i][4] + bias[4]; o1.y = acc[i][5] + bias[5];
    o1.z = acc[i][6] + bias[6]; o1.w = acc[i][7] + bias[7];
    *(float4*)&PRE[row * PRE_STRIDE + tx * 8] = o0;
    *(float4*)&PRE[row * PRE_STRIDE + tx * 8 + 4] = o1;
  }
  {
    const float bf0 = bfp[0], bi0 = bip[0], bg0 = bgp[0], bo0 = bop[0];
    const float ab = (gp == 0) ? bf0 : bg0;
    const float bb = (gp == 0) ? bi0 : bo0;
    const size_t row = rowbase + r2;
    float2 og;
    og.x = ga + ab; og.y = gb + bb;
    *(float2*)&PRE[row * PRE_STRIDE + 128 + gp] = og;
  }
}

// ---------------------------------------------------------------------------
// Kernel 3: serial recurrence. One wave (64 lanes) per batch element.
// R3 post-mortem: VGPR_Count stayed 64 despite __launch_bounds__(64,1) — the
// compiler will not give this wave a big register file, so w2r[64] kept
// round-tripping through scratch every step (~64 VMEM ops/step = the 2700
// cy/step). Fix: stop needing registers — stage W2 TRANSPOSED into LDS once
// (W2T[32][132], 16B-aligned rows) and read 16 x ds_read_b128 per step.
// Loop-resident state drops to ~50 VGPRs; no spill possible.
// ---------------------------------------------------------------------------
__device__ __forceinline__ void lds_fence_wave() {
  asm volatile("s_waitcnt lgkmcnt(0)" ::: "memory");
}

__device__ __forceinline__ float sigmoid_f(float x) {
  return __fdividef(1.0f, 1.0f + __expf(-x));
}
__device__ __forceinline__ float tanh_f(float x) {
  const float e = __expf(-2.0f * x);
  return __fdividef(1.0f - e, 1.0f + e);
}
// cumprod-of-8 mean from two float4s (no memory array)
__device__ __forceinline__ float qgate_v(const float4 a, const float4 b) {
  float p = a.x, s = a.x;
  p *= a.y; s += p;
  p *= a.z; s += p;
  p *= a.w; s += p;
  p *= b.x; s += p;
  p *= b.y; s += p;
  p *= b.z; s += p;
  p *= b.w; s += p;
  return s * 0.125f;
}

#define W2LD 132  // LDS row stride for W2T (x4B = 528B, 16B-aligned)

__global__ __attribute__((amdgpu_waves_per_eu(1, 1))) __launch_bounds__(64)
void rec_kernel(
    const float* __restrict__ PRE, const float* __restrict__ W2,
    const float* __restrict__ b2, const float* __restrict__ aux,
    float* __restrict__ out) {
  __shared__ __align__(16) float W2T[32 * W2LD + 4];  // W2T[m][j] = W2[j][m]
  __shared__ __align__(16) float h1s[128];
  __shared__ __align__(16) float csh[32];

  const int l = threadIdx.x;
  const int b = blockIdx.x;
  const int m = l & 31, half = l >> 5;

  // ---- stage W2 (128x32, row-major) transposed into LDS, once ----
  // pass it: lane l loads float4 at element e = (it*64 + l)*4 — elements
  // e..e+3 are row j = e>>5, cols m0..m0+3 with m0 = e&31.
#pragma unroll 4
  for (int it = 0; it < 16; ++it) {
    const int e = (it * 64 + l) * 4;
    const float4 v = *(const float4*)&W2[e];
    const int j = e >> 5, m0 = e & 31;
    W2T[(m0 + 0) * W2LD + j] = v.x;
    W2T[(m0 + 1) * W2LD + j] = v.y;
    W2T[(m0 + 2) * W2LD + j] = v.z;
    W2T[(m0 + 3) * W2LD + j] = v.w;
  }

  const float b2v = b2[m];
  const float2 s1 = *(const float2*)&aux[2 * l];
  const float4 sg = *(const float4*)&aux[128];  // sf, si, sg, so

  float h = 0.f, c = 0.f;

  const float* pr0 = PRE + (size_t)b * PRE_STRIDE;
  const size_t tstride = (size_t)BATCH * PRE_STRIDE;

  // depth-3 prefetch pipeline
  float2 p0 = *(const float2*)(pr0 + 0 * tstride + 2 * l);
  float4 g0 = *(const float4*)(pr0 + 0 * tstride + 128);
  float2 p1 = *(const float2*)(pr0 + 1 * tstride + 2 * l);
  float4 g1 = *(const float4*)(pr0 + 1 * tstride + 128);
  float2 p2 = *(const float2*)(pr0 + 2 * tstride + 2 * l);
  float4 g2 = *(const float4*)(pr0 + 2 * tstride + 128);

  // per-lane LDS base pointers for the matvec
  const float4* w2p = (const float4*)&W2T[m * W2LD + half * 64];
  const float4* h1p = (const float4*)&h1s[half * 64];

  lds_fence_wave();  // W2T staging visible before first use (in-order DS)

  for (int t = 0; t < SEQ; ++t) {
    // h1 = relu(pre + h*s1)   (b1 already folded into PRE)
    const float h10 = fmaxf(fmaf(h, s1.x, p0.x), 0.f);
    const float h11 = fmaxf(fmaf(h, s1.y, p0.y), 0.f);
    // classical gate pre-activations
    const float zf = fmaf(h, sg.x, g0.x);
    const float zi = fmaf(h, sg.y, g0.y);
    const float zg = fmaf(h, sg.z, g0.z);
    const float zo = fmaf(h, sg.w, g0.w);
    // rotate prefetch (distance 3)
    p0 = p1; g0 = g1; p1 = p2; g1 = g2;
    const int tn = (t + 3 < SEQ) ? (t + 3) : (SEQ - 1);
    p2 = *(const float2*)(pr0 + (size_t)tn * tstride + 2 * l);
    g2 = *(const float4*)(pr0 + (size_t)tn * tstride + 128);

    // broadcast h1 through LDS (wave-level fence, no barrier)
    ((float2*)h1s)[l] = make_float2(h10, h11);
    lds_fence_wave();

    // q[m] = sum_j h1[j] * W2[j][m] — lane (m,half) sums 64 j's.
    // h1 reads: 32 lanes/address (broadcast). W2T reads: 64 distinct 16B.
    float q0 = 0.f, q1 = 0.f, q2 = 0.f, q3 = 0.f;
#pragma unroll
    for (int jj = 0; jj < 16; ++jj) {
      const float4 hv = h1p[jj];
      const float4 wv = w2p[jj];
      q0 = fmaf(hv.x, wv.x, q0);
      q1 = fmaf(hv.y, wv.y, q1);
      q2 = fmaf(hv.z, wv.z, q2);
      q3 = fmaf(hv.w, wv.w, q3);
    }
    const float qh = (q0 + q1) + (q2 + q3);
    const float theta = qh + __shfl_xor(qh, 32, 64) + b2v;
    const float cv = __cosf(theta);
    if (l < 32) csh[m] = cv;
    lds_fence_wave();

    // every lane reads all 32 cos values (8 float4s, named regs — no array)
    const float4 c0v = ((const float4*)csh)[0];
    const float4 c1v = ((const float4*)csh)[1];
    const float4 c2v = ((const float4*)csh)[2];
    const float4 c3v = ((const float4*)csh)[3];
    const float4 c4v = ((const float4*)csh)[4];
    const float4 c5v = ((const float4*)csh)[5];
    const float4 c6v = ((const float4*)csh)[6];
    const float4 c7v = ((const float4*)csh)[7];
    const float qf = qgate_v(c0v, c1v);
    const float qi = qgate_v(c2v, c3v);
    const float qg = qgate_v(c4v, c5v);
    const float qo = qgate_v(c6v, c7v);

    const float f  = 0.5f * (sigmoid_f(zf) + sigmoid_f(qf));
    const float ii = 0.5f * (sigmoid_f(zi) + sigmoid_f(qi));
    const float gg = 0.5f * (tanh_f(zg) + tanh_f(qg));
    const float oo = 0.5f * (sigmoid_f(zo) + sigmoid_f(qo));

    c = fmaf(f, c, ii * gg);
    h = oo * tanh_f(c);

    float4 hv4o; hv4o.x = h; hv4o.y = h; hv4o.z = h; hv4o.w = h;
    *(float4*)(out + ((size_t)t * BATCH + b) * 256 + 4 * l) = hv4o;
  }

  // final (hx, cx) outputs
  float4 hq; hq.x = h; hq.y = h; hq.z = h; hq.w = h;
  float4 cq; cq.x = c; cq.y = c; cq.z = c; cq.w = c;
  *(float4*)(out + (size_t)SEQ * BATCH * 256 + (size_t)b * 256 + 4 * l) = hq;
  *(float4*)(out + (size_t)SEQ * BATCH * 256 + (size_t)BATCH * 256 +
             (size_t)b * 256 + 4 * l) = cq;
}

// ---------------------------------------------------------------------------
extern "C" void kernel_launch(void* const* d_in, const int* in_sizes, int n_in,
                              void* d_out, int out_size, void* d_ws,
                              size_t ws_size, hipStream_t stream) {
  const float* X  = (const float*)d_in[0];
  const float* W1 = (const float*)d_in[1];
  const float* b1 = (const float*)d_in[2];
  const float* W2 = (const float*)d_in[3];
  const float* b2 = (const float*)d_in[4];
  const float* Wf = (const float*)d_in[5];
  const float* bf = (const float*)d_in[6];
  const float* Wi = (const float*)d_in[7];
  const float* bi = (const float*)d_in[8];
  const float* Wg = (const float*)d_in[9];
  const float* bg = (const float*)d_in[10];
  const float* Wo = (const float*)d_in[11];
  const float* bo = (const float*)d_in[12];

  float* ws  = (float*)d_ws;
  float* PRE = ws;
  float* aux = ws + AUX_OFF;
  float* out = (float*)d_out;

  prep_kernel<<<1, 256, 0, stream>>>(W1, Wf, Wi, Wg, Wo, bf, bi, bg, bo, aux);
  gemm_kernel<<<M_ROWS / 128, 256, 0, stream>>>(X, W1, b1, Wf, Wi, Wg, Wo,
                                                bf, bi, bg, bo, PRE);
  rec_kernel<<<BATCH, 64, 0, stream>>>(PRE, W2, b2, aux, out);
}

// Round 5
// 796.392 us; speedup vs baseline: 1.1180x; 1.0832x over previous
//
#include <hip/hip_runtime.h>

#define SEQ 512
#define BATCH 256
#define INDIM 256
#define MLP 128
#define M_ROWS (SEQ * BATCH)        // 131072
#define PRE_STRIDE 136              // 128 mlp-pre + 4 gate-pre + 4 pad
#define AUX_OFF ((size_t)M_ROWS * PRE_STRIDE)  // in floats

// ---------------------------------------------------------------------------
// Kernel 1: prep — column sums of the recurrent halves of W1 and gate weights.
// ---------------------------------------------------------------------------
__global__ __launch_bounds__(256) void prep_kernel(
    const float* __restrict__ W1,
    const float* __restrict__ Wf, const float* __restrict__ Wi,
    const float* __restrict__ Wg, const float* __restrict__ Wo,
    const float* __restrict__ bf, const float* __restrict__ bi,
    const float* __restrict__ bg, const float* __restrict__ bo,
    float* __restrict__ aux) {
  const int tid = threadIdx.x;
  if (tid < 128) {
    float s = 0.f;
    for (int k = 0; k < 256; ++k) s += W1[(size_t)(256 + k) * 128 + tid];
    aux[tid] = s;
  } else if (tid < 132) {
    const int g = tid - 128;
    const float* w = (g == 0) ? Wf : (g == 1) ? Wi : (g == 2) ? Wg : Wo;
    float s = 0.f;
    for (int k = 0; k < 256; ++k) s += w[256 + k];
    aux[128 + g] = s;
  } else if (tid < 136) {
    const int g = tid - 132;
    const float* bp = (g == 0) ? bf : (g == 1) ? bi : (g == 2) ? bg : bo;
    aux[132 + g] = bp[0];
  }
}

// ---------------------------------------------------------------------------
// Kernel 2: big fp32 GEMM over all (t,b) rows. (unchanged this round)
// ---------------------------------------------------------------------------
#define BK 16
#define LDX 132  // padded LDS row stride (words)

__global__ __launch_bounds__(256) void gemm_kernel(
    const float* __restrict__ X,    // [M_ROWS][256]
    const float* __restrict__ W1,   // [512][128] (only rows 0..255 used here)
    const float* __restrict__ b1p,  // [128]
    const float* __restrict__ Wf, const float* __restrict__ Wi,
    const float* __restrict__ Wg, const float* __restrict__ Wo,
    const float* __restrict__ bfp, const float* __restrict__ bip,
    const float* __restrict__ bgp, const float* __restrict__ bop,
    float* __restrict__ PRE) {
  __shared__ __align__(16) float Xs[BK * LDX];   // [kk][row], row-padded
  __shared__ __align__(16) float Ws[BK * LDX];   // [kk][col]
  __shared__ float Wgs[BK * 4];                  // [kk][gate]

  const int tid = threadIdx.x;
  const int blk = blockIdx.x;
  const int tx = tid & 15, ty = tid >> 4;       // 16x16 thread grid
  const int r_st = tid >> 1, kh = (tid & 1) * 8; // X staging role
  const int wk = tid >> 4, wn = (tid & 15) * 8;  // W staging role
  const int r2 = tid >> 1, gp = (tid & 1) * 2;   // gate compute role

  const size_t rowbase = (size_t)blk * 128;

  float acc[8][8] = {};
  float ga = 0.f, gb = 0.f;

  for (int kc = 0; kc < 256; kc += BK) {
    const float4 xa = *(const float4*)&X[(rowbase + r_st) * 256 + kc + kh];
    const float4 xb = *(const float4*)&X[(rowbase + r_st) * 256 + kc + kh + 4];
    const float4 wa = *(const float4*)&W1[(size_t)(kc + wk) * 128 + wn];
    const float4 wb = *(const float4*)&W1[(size_t)(kc + wk) * 128 + wn + 4];
    float wgv = 0.f;
    if (tid < 64) {
      const int kk = tid >> 2, g = tid & 3;
      const float* w = (g == 0) ? Wf : (g == 1) ? Wi : (g == 2) ? Wg : Wo;
      wgv = w[kc + kk];
    }
    __syncthreads();  // previous chunk's compute must be done before overwrite
    Xs[(kh + 0) * LDX + r_st] = xa.x;
    Xs[(kh + 1) * LDX + r_st] = xa.y;
    Xs[(kh + 2) * LDX + r_st] = xa.z;
    Xs[(kh + 3) * LDX + r_st] = xa.w;
    Xs[(kh + 4) * LDX + r_st] = xb.x;
    Xs[(kh + 5) * LDX + r_st] = xb.y;
    Xs[(kh + 6) * LDX + r_st] = xb.z;
    Xs[(kh + 7) * LDX + r_st] = xb.w;
    *(float4*)&Ws[wk * LDX + wn] = wa;
    *(float4*)&Ws[wk * LDX + wn + 4] = wb;
    if (tid < 64) Wgs[tid] = wgv;
    __syncthreads();

#pragma unroll
    for (int kk = 0; kk < BK; ++kk) {
      const float4 a0 = *(const float4*)&Xs[kk * LDX + ty * 8];
      const float4 a1 = *(const float4*)&Xs[kk * LDX + ty * 8 + 4];
      const float4 c0 = *(const float4*)&Ws[kk * LDX + tx * 8];
      const float4 c1 = *(const float4*)&Ws[kk * LDX + tx * 8 + 4];
      const float av[8] = {a0.x, a0.y, a0.z, a0.w, a1.x, a1.y, a1.z, a1.w};
      const float bv[8] = {c0.x, c0.y, c0.z, c0.w, c1.x, c1.y, c1.z, c1.w};
#pragma unroll
      for (int i = 0; i < 8; ++i)
#pragma unroll
        for (int j = 0; j < 8; ++j)
          acc[i][j] = fmaf(av[i], bv[j], acc[i][j]);
      const float xv = Xs[kk * LDX + r2];
      ga = fmaf(xv, Wgs[kk * 4 + gp], ga);
      gb = fmaf(xv, Wgs[kk * 4 + gp + 1], gb);
    }
  }

  float bias[8];
  {
    const float4 u0 = *(const float4*)&b1p[tx * 8];
    const float4 u1 = *(const float4*)&b1p[tx * 8 + 4];
    bias[0] = u0.x; bias[1] = u0.y; bias[2] = u0.z; bias[3] = u0.w;
    bias[4] = u1.x; bias[5] = u1.y; bias[6] = u1.z; bias[7] = u1.w;
  }
#pragma unroll
  for (int i = 0; i < 8; ++i) {
    const size_t row = rowbase + ty * 8 + i;
    float4 o0, o1;
    o0.x = acc[i][0] + bias[0]; o0.y = acc[i][1] + bias[1];
    o0.z = acc[i][2] + bias[2]; o0.w = acc[i][3] + bias[3];
    o1.x = acc[i][4] + bias[4]; o1.y = acc[i][5] + bias[5];
    o1.z = acc[i][6] + bias[6]; o1.w = acc[i][7] + bias[7];
    *(float4*)&PRE[row * PRE_STRIDE + tx * 8] = o0;
    *(float4*)&PRE[row * PRE_STRIDE + tx * 8 + 4] = o1;
  }
  {
    const float bf0 = bfp[0], bi0 = bip[0], bg0 = bgp[0], bo0 = bop[0];
    const float ab = (gp == 0) ? bf0 : bg0;
    const float bb = (gp == 0) ? bi0 : bo0;
    const size_t row = rowbase + r2;
    float2 og;
    og.x = ga + ab; og.y = gb + bb;
    *(float2*)&PRE[row * PRE_STRIDE + 128 + gp] = og;
  }
}

// ---------------------------------------------------------------------------
// Kernel 3: serial recurrence. One wave per batch element.
// R4 post-mortem: spills were NOT the bottleneck (VGPR 64->132 changed
// nothing). The step's latency chain was: 2 LDS roundtrips w/ full lgkm
// drains + 32 ds_read_b128/step (static W2 re-read!) + shfl + ~12 redundant
// transcendental chains. This version: W2 in registers (budget now provably
// >=132 via amdgpu_waves_per_eu(1,1)), ONE LDS roundtrip (h1 broadcast),
// qgate via shfl-gather (8+4 shfls), ONE quantum activation per lane via
// tanh(x) = 2*sigmoid(2x)-1, classical activations hoisted for ILP.
// ---------------------------------------------------------------------------
__device__ __forceinline__ void lds_fence_wave() {
  asm volatile("s_waitcnt lgkmcnt(0)" ::: "memory");
}

__device__ __forceinline__ float sigmoid_f(float x) {
  return __fdividef(1.0f, 1.0f + __expf(-x));
}
__device__ __forceinline__ float tanh_f(float x) {
  const float e = __expf(-2.0f * x);
  return __fdividef(1.0f - e, 1.0f + e);
}

__global__ __attribute__((amdgpu_waves_per_eu(1, 1))) __launch_bounds__(64)
void rec_kernel(
    const float* __restrict__ PRE, const float* __restrict__ W2,
    const float* __restrict__ b2, const float* __restrict__ aux,
    float* __restrict__ out) {
  __shared__ __align__(16) float h1s[128];

  const int l = threadIdx.x;
  const int b = blockIdx.x;
  const int m = l & 31, half = l >> 5;
  const int g = m >> 3;           // gate group: 0=f 1=i 2=g 3=o
  const int gbase = g * 8;        // first lane of my group's cos values

  // W2 fragment in REGISTERS: lane (m,half) holds W2[half*64+u][m], u=0..63
  float w2r[64];
#pragma unroll
  for (int u = 0; u < 64; ++u) w2r[u] = W2[(size_t)(half * 64 + u) * 32 + m];
  const float b2v = b2[m];
  const float2 s1 = *(const float2*)&aux[2 * l];
  const float4 sg = *(const float4*)&aux[128];  // sf, si, sg, so

  float h = 0.f, c = 0.f;

  const float* pr0 = PRE + (size_t)b * PRE_STRIDE;
  const size_t tstride = (size_t)BATCH * PRE_STRIDE;

  // depth-3 prefetch pipeline
  float2 p0 = *(const float2*)(pr0 + 0 * tstride + 2 * l);
  float4 g0 = *(const float4*)(pr0 + 0 * tstride + 128);
  float2 p1 = *(const float2*)(pr0 + 1 * tstride + 2 * l);
  float4 g1 = *(const float4*)(pr0 + 1 * tstride + 128);
  float2 p2 = *(const float2*)(pr0 + 2 * tstride + 2 * l);
  float4 g2 = *(const float4*)(pr0 + 2 * tstride + 128);

  const float4* h1p = (const float4*)&h1s[half * 64];

  for (int t = 0; t < SEQ; ++t) {
    // h1 = relu(pre + h*s1)   (b1 already folded into PRE)
    const float h10 = fmaxf(fmaf(h, s1.x, p0.x), 0.f);
    const float h11 = fmaxf(fmaf(h, s1.y, p0.y), 0.f);
    // classical gate pre-activations + their activations (off critical path;
    // independent of the matvec -> overlaps the LDS latency)
    const float zf = fmaf(h, sg.x, g0.x);
    const float zi = fmaf(h, sg.y, g0.y);
    const float zg = fmaf(h, sg.z, g0.z);
    const float zo = fmaf(h, sg.w, g0.w);
    const float cf = sigmoid_f(zf);
    const float ci = sigmoid_f(zi);
    const float cg = tanh_f(zg);
    const float co = sigmoid_f(zo);
    // rotate prefetch (distance 3)
    p0 = p1; g0 = g1; p1 = p2; g1 = g2;
    const int tn = (t + 3 < SEQ) ? (t + 3) : (SEQ - 1);
    p2 = *(const float2*)(pr0 + (size_t)tn * tstride + 2 * l);
    g2 = *(const float4*)(pr0 + (size_t)tn * tstride + 128);

    // ---- the ONLY LDS roundtrip: broadcast h1 ----
    ((float2*)h1s)[l] = make_float2(h10, h11);
    lds_fence_wave();

    // q[m] = sum_j h1[j] * W2[j][m] — lane (m,half) sums 64 j's from regs
    float q0 = 0.f, q1 = 0.f, q2 = 0.f, q3 = 0.f;
#pragma unroll
    for (int jj = 0; jj < 16; ++jj) {
      const float4 hv = h1p[jj];
      q0 = fmaf(hv.x, w2r[4 * jj + 0], q0);
      q1 = fmaf(hv.y, w2r[4 * jj + 1], q1);
      q2 = fmaf(hv.z, w2r[4 * jj + 2], q2);
      q3 = fmaf(hv.w, w2r[4 * jj + 3], q3);
    }
    const float qh = (q0 + q1) + (q2 + q3);
    const float theta = qh + __shfl_xor(qh, 32, 64) + b2v;
    const float cv = __cosf(theta);   // every lane holds cos(theta[m])

    // gather the 8 cos values of my gate group via shfl (no LDS roundtrip)
    const float e0 = __shfl(cv, gbase + 0, 64);
    const float e1 = __shfl(cv, gbase + 1, 64);
    const float e2 = __shfl(cv, gbase + 2, 64);
    const float e3 = __shfl(cv, gbase + 3, 64);
    const float e4 = __shfl(cv, gbase + 4, 64);
    const float e5 = __shfl(cv, gbase + 5, 64);
    const float e6 = __shfl(cv, gbase + 6, 64);
    const float e7 = __shfl(cv, gbase + 7, 64);
    float p = e0, s = e0;
    p *= e1; s += p;
    p *= e2; s += p;
    p *= e3; s += p;
    p *= e4; s += p;
    p *= e5; s += p;
    p *= e6; s += p;
    p *= e7; s += p;
    const float qv = s * 0.125f;      // my group's qgate mean

    // ONE quantum activation per lane; tanh via 2*sigmoid(2x)-1 for group 2
    const float qarg = (g == 2) ? (2.0f * qv) : qv;
    const float qs = sigmoid_f(qarg);
    const float av = (g == 2) ? (2.0f * qs - 1.0f) : qs;

    // collect the 4 activated quantum gates (groups live at lanes 0,8,16,24)
    const float aF = __shfl(av, 0, 64);
    const float aI = __shfl(av, 8, 64);
    const float aG = __shfl(av, 16, 64);
    const float aO = __shfl(av, 24, 64);

    const float f  = 0.5f * (cf + aF);
    const float ii = 0.5f * (ci + aI);
    const float gg = 0.5f * (cg + aG);
    const float oo = 0.5f * (co + aO);

    c = fmaf(f, c, ii * gg);
    h = oo * tanh_f(c);

    float4 hv4o; hv4o.x = h; hv4o.y = h; hv4o.z = h; hv4o.w = h;
    *(float4*)(out + ((size_t)t * BATCH + b) * 256 + 4 * l) = hv4o;
  }

  // final (hx, cx) outputs
  float4 hq; hq.x = h; hq.y = h; hq.z = h; hq.w = h;
  float4 cq; cq.x = c; cq.y = c; cq.z = c; cq.w = c;
  *(float4*)(out + (size_t)SEQ * BATCH * 256 + (size_t)b * 256 + 4 * l) = hq;
  *(float4*)(out + (size_t)SEQ * BATCH * 256 + (size_t)BATCH * 256 +
             (size_t)b * 256 + 4 * l) = cq;
}

// ---------------------------------------------------------------------------
extern "C" void kernel_launch(void* const* d_in, const int* in_sizes, int n_in,
                              void* d_out, int out_size, void* d_ws,
                              size_t ws_size, hipStream_t stream) {
  const float* X  = (const float*)d_in[0];
  const float* W1 = (const float*)d_in[1];
  const float* b1 = (const float*)d_in[2];
  const float* W2 = (const float*)d_in[3];
  const float* b2 = (const float*)d_in[4];
  const float* Wf = (const float*)d_in[5];
  const float* bf = (const float*)d_in[6];
  const float* Wi = (const float*)d_in[7];
  const float* bi = (const float*)d_in[8];
  const float* Wg = (const float*)d_in[9];
  const float* bg = (const float*)d_in[10];
  const float* Wo = (const float*)d_in[11];
  const float* bo = (const float*)d_in[12];

  float* ws  = (float*)d_ws;
  float* PRE = ws;
  float* aux = ws + AUX_OFF;
  float* out = (float*)d_out;

  prep_kernel<<<1, 256, 0, stream>>>(W1, Wf, Wi, Wg, Wo, bf, bi, bg, bo, aux);
  gemm_kernel<<<M_ROWS / 128, 256, 0, stream>>>(X, W1, b1, Wf, Wi, Wg, Wo,
                                                bf, bi, bg, bo, PRE);
  rec_kernel<<<BATCH, 64, 0, stream>>>(PRE, W2, b2, aux, out);
}